// Round 3
// baseline (194.826 us; speedup 1.0000x reference)
//
#include <hip/hip_runtime.h>
#include <math.h>

#define N_NODES 50000
#define N_EDGES 1600000
#define N_RELS 8
#define N_BASES 4
#define HD 64

#define NB_D 196                 // ceil(50000/256) blocks in d_table_kernel
#define NB_E 1563                // edge kernel: 1563*256 = 400128 threads, 1 quad each
#define NQUAD (N_EDGES / 4)      // 400000

typedef int      vint4  __attribute__((ext_vector_type(4)));
typedef float    vfloat4 __attribute__((ext_vector_type(4)));
typedef _Float16 half4v __attribute__((ext_vector_type(4)));   // 8B: one (r,v) D entry
typedef _Float16 half8v __attribute__((ext_vector_type(8)));   // 16B: two entries (store side)

// ws layout (floats):
//   G[27][64]   at G_OFF      [0..1728)
//   partials    at PART_OFF   [1728..1728+NB_D+NB_E) = [1728..3487)
//   ticket(int) at TICKET_OFF [3488]
//   D           at D_OFF      v-major fp16: half4v index = v*8 + r
//                             (d0,d1,d2,0) per (v,r) -> 8B, 64B per node, 3.2 MB total
//                             -> fits one XCD's 4 MB L2 entirely.
#define G_OFF      0
#define PART_OFF   1728
#define TICKET_OFF 3488
#define D_OFF      4096

// ---------------------------------------------------------------------------
// Build G[27][64]. One 256-thread block. Also resets the edge-kernel ticket.
__global__ void prep_kernel(const float* __restrict__ W_in,
                            const float* __restrict__ b_in,
                            const float* __restrict__ w_comp,
                            const float* __restrict__ bases,
                            const float* __restrict__ loop_w,
                            const float* __restrict__ h_bias,
                            float* __restrict__ G,
                            int* __restrict__ ticket) {
    __shared__ float sA[N_BASES * 3 * HD];   // A[b][k][o]
    const int tid = threadIdx.x;
    const int o = tid & 63;
    const int b = tid >> 6;                  // 0..3

    if (tid == 0) *ticket = 0;               // per-launch reset (prep serializes first)

    // A[b][k][o] = sum_i winrow_k[i] * bases[b,i,o]
    {
        float s0 = 0.f, s1 = 0.f, sb = 0.f;
        for (int i = 0; i < HD; i++) {
            float bv = bases[b * HD * HD + i * HD + o];
            s0 += W_in[i]      * bv;
            s1 += W_in[HD + i] * bv;
            sb += b_in[i]      * bv;
        }
        sA[(b * 3 + 0) * HD + o] = s0;
        sA[(b * 3 + 1) * HD + o] = s1;
        sA[(b * 3 + 2) * HD + o] = sb;
    }
    __syncthreads();

    // G[j][o] = sum_b w_comp[r,b] * A[b][k][o],  j = 3r+k
    for (int idx = tid; idx < 24 * HD; idx += 256) {
        int j = idx >> 6, oo = idx & 63;
        int r = j / 3, k = j % 3;
        float s = 0.f;
#pragma unroll
        for (int bb = 0; bb < N_BASES; bb++)
            s += w_comp[r * N_BASES + bb] * sA[(bb * 3 + k) * HD + oo];
        G[j * HD + oo] = s;
    }

    // self-loop columns j=24,25,26
    if (tid < 3 * HD) {
        int k = tid >> 6, oo = tid & 63;
        float s = 0.f;
        for (int i = 0; i < HD; i++) {
            float w = (k == 0) ? W_in[i] : (k == 1) ? W_in[HD + i] : b_in[i];
            s += w * loop_w[i * HD + oo];
        }
        if (k == 2) s += h_bias[oo];
        G[(24 + k) * HD + oo] = s;
    }
}

// ---------------------------------------------------------------------------
// D entry (v,r) = (fcW_v·g_{r,0}, fcW_v·g_{r,1}, fcW_v·g_{r,2}, 0) in fp16,
// v-major so each node's 8 relations share one 64B line.
// fc_W is a 12.8 MB one-shot stream -> nontemporal, keep L2 for D/feat.
__global__ __launch_bounds__(256) void d_table_kernel(
        const vfloat4* __restrict__ fcW4,
        const float2* __restrict__ feat,
        const float* __restrict__ G,
        half8v* __restrict__ D16,        // index v*4 + j, j-th pair of relations
        float* __restrict__ partD) {
    const int v = blockIdx.x * 256 + threadIdx.x;
    float part = 0.f;

    if (v < N_NODES) {
        vfloat4 Fr[16];
#pragma unroll
        for (int k = 0; k < 16; k++) Fr[k] = __builtin_nontemporal_load(&fcW4[v * 16 + k]);

        float s[27];
#pragma unroll
        for (int j = 0; j < 27; j++) {
            float acc = 0.f;
#pragma unroll
            for (int k = 0; k < 16; k++) {
                // uniform addresses -> scalar loads, broadcast
                float gx = G[j * HD + 4 * k + 0];
                float gy = G[j * HD + 4 * k + 1];
                float gz = G[j * HD + 4 * k + 2];
                float gw = G[j * HD + 4 * k + 3];
                acc += Fr[k].x * gx + Fr[k].y * gy + Fr[k].z * gz + Fr[k].w * gw;
            }
            s[j] = acc;
        }

        // pack rels (2j, 2j+1) into one 16B store; node v occupies D16[v*4 .. v*4+4)
#pragma unroll
        for (int j = 0; j < 4; j++) {
            half8v pk;
            pk[0] = (_Float16)s[6 * j + 0];
            pk[1] = (_Float16)s[6 * j + 1];
            pk[2] = (_Float16)s[6 * j + 2];
            pk[3] = (_Float16)0.f;
            pk[4] = (_Float16)s[6 * j + 3];
            pk[5] = (_Float16)s[6 * j + 4];
            pk[6] = (_Float16)s[6 * j + 5];
            pk[7] = (_Float16)0.f;
            D16[v * 4 + j] = pk;
        }

        float2 f = feat[v];
        part = s[24] * f.x + s[25] * f.y + s[26];
    }

    // shuffle block reduce (wave64), single barrier
    for (int off = 32; off; off >>= 1) part += __shfl_down(part, off);
    __shared__ float wred[4];
    if ((threadIdx.x & 63) == 0) wred[threadIdx.x >> 6] = part;
    __syncthreads();
    if (threadIdx.x == 0) partD[blockIdx.x] = wred[0] + wred[1] + wred[2] + wred[3];
}

// ---------------------------------------------------------------------------
// Pure gather over edges: 1 quad per thread (11 loads in flight), 6252 waves
// for latency hiding. D gathers are 8B from an L2-resident 3.2 MB table.
// Last-done block (ticket) reduces all partials, applies bias+sigmoid,
// writes out.
__global__ __launch_bounds__(256) void edge_gather_kernel(
        const vint4* __restrict__ src4,
        const vint4* __restrict__ dst4,
        const vint4* __restrict__ et4,
        const float2* __restrict__ feat,
        const half4v* __restrict__ D8,  // index v*8 + r
        float* __restrict__ part,       // full partials array [NB_D + NB_E]
        int* __restrict__ ticket,
        const float* __restrict__ fc_b,
        float* __restrict__ out) {
    const int t = blockIdx.x * 256 + threadIdx.x;
    float s = 0.f;

    if (t < NQUAD) {
        vint4 u = __builtin_nontemporal_load(&src4[t]);
        vint4 v = __builtin_nontemporal_load(&dst4[t]);
        vint4 r = __builtin_nontemporal_load(&et4[t]);

        float2 f0 = feat[u.x];
        float2 f1 = feat[u.y];
        float2 f2 = feat[u.z];
        float2 f3 = feat[u.w];
        half4v h0 = D8[v.x * 8 + r.x];
        half4v h1 = D8[v.y * 8 + r.y];
        half4v h2 = D8[v.z * 8 + r.z];
        half4v h3 = D8[v.w * 8 + r.w];

        s  = f0.x * (float)h0.x + f0.y * (float)h0.y + (float)h0.z;
        s += f1.x * (float)h1.x + f1.y * (float)h1.y + (float)h1.z;
        s += f2.x * (float)h2.x + f2.y * (float)h2.y + (float)h2.z;
        s += f3.x * (float)h3.x + f3.y * (float)h3.y + (float)h3.z;
    }

    // shuffle block reduce
    for (int off = 32; off; off >>= 1) s += __shfl_down(s, off);
    __shared__ float wred[4];
    __shared__ int lastFlag;
    if ((threadIdx.x & 63) == 0) wred[threadIdx.x >> 6] = s;
    __syncthreads();
    if (threadIdx.x == 0) {
        part[NB_D + blockIdx.x] = wred[0] + wred[1] + wred[2] + wred[3];
        __threadfence();                                   // release partial
        int tk = atomicAdd(ticket, 1);                     // device-scope
        lastFlag = (tk == NB_E - 1);
    }
    __syncthreads();

    if (lastFlag) {
        __threadfence();                                   // acquire
        float fs = 0.f;
        for (int i = threadIdx.x; i < NB_D + NB_E; i += 256) {
            // agent-scope load: served at the coherent point — partials were
            // written by blocks on other XCDs (per-XCD L2 not coherent).
            fs += __hip_atomic_load(&part[i], __ATOMIC_RELAXED, __HIP_MEMORY_SCOPE_AGENT);
        }
        for (int off = 32; off; off >>= 1) fs += __shfl_down(fs, off);
        if ((threadIdx.x & 63) == 0) wred[threadIdx.x >> 6] = fs;
        __syncthreads();
        if (threadIdx.x == 0) {
            float x = wred[0] + wred[1] + wred[2] + wred[3] + fc_b[0];
            out[0] = 1.0f / (1.0f + expf(-x));
        }
    }
}

// ---------------------------------------------------------------------------
extern "C" void kernel_launch(void* const* d_in, const int* in_sizes, int n_in,
                              void* d_out, int out_size, void* d_ws, size_t ws_size,
                              hipStream_t stream) {
    const float* features = (const float*)d_in[0];
    const int*   src      = (const int*)d_in[1];
    const int*   dst      = (const int*)d_in[2];
    const int*   etype    = (const int*)d_in[3];
    const float* W_in     = (const float*)d_in[4];
    const float* b_in     = (const float*)d_in[5];
    const float* w_comp   = (const float*)d_in[6];
    const float* bases    = (const float*)d_in[7];
    const float* loop_w   = (const float*)d_in[8];
    const float* h_bias   = (const float*)d_in[9];
    const float* fc_W     = (const float*)d_in[10];
    const float* fc_b     = (const float*)d_in[11];

    float* ws      = (float*)d_ws;
    float* G       = ws + G_OFF;
    float* part    = ws + PART_OFF;
    int*   ticket  = (int*)(ws + TICKET_OFF);
    half8v* D16    = (half8v*)(ws + D_OFF);
    half4v* D8     = (half4v*)(ws + D_OFF);
    float* out     = (float*)d_out;

    prep_kernel<<<1, 256, 0, stream>>>(W_in, b_in, w_comp, bases, loop_w, h_bias, G, ticket);
    d_table_kernel<<<NB_D, 256, 0, stream>>>(
        (const vfloat4*)fc_W, (const float2*)features, G, D16, part);
    edge_gather_kernel<<<NB_E, 256, 0, stream>>>(
        (const vint4*)src, (const vint4*)dst, (const vint4*)etype,
        (const float2*)features, D8, part, ticket, fc_b, out);
}

// Round 5
// 146.386 us; speedup vs baseline: 1.3309x; 1.3309x over previous
//
#include <hip/hip_runtime.h>
#include <math.h>

#define N_NODES 50000
#define N_EDGES 1600000
#define N_RELS 8
#define N_BASES 4
#define HD 64

#define NB_D 196                 // ceil(50000/256) blocks in d_table_kernel
#define NB_E 782                 // edge kernel: 782*256 threads * 2 quads = 400384 >= 400000
#define NTHR_E (NB_E * 256)      // 200192
#define NQUAD (N_EDGES / 4)      // 400000

typedef int      vint4   __attribute__((ext_vector_type(4)));
typedef float    vfloat4 __attribute__((ext_vector_type(4)));
typedef _Float16 half4v  __attribute__((ext_vector_type(4)));   // 8B: one (v,r) D entry
typedef _Float16 half8v  __attribute__((ext_vector_type(8)));   // 16B: two entries (store side)

// ws layout (floats):
//   G[27][64]   at G_OFF      [0..1728)
//   partials    at PART_OFF   [1728..1728+NB_D+NB_E) = [1728..2706)
//   D           at D_OFF      v-major fp16: half4v index = v*8 + r
//                             (d0,d1,d2,0) per (v,r) -> 8B, 64B per node, 3.2 MB total
#define G_OFF      0
#define PART_OFF   1728
#define D_OFF      4096

// ---------------------------------------------------------------------------
// Build G[27][64]. One 256-thread block.
__global__ void prep_kernel(const float* __restrict__ W_in,
                            const float* __restrict__ b_in,
                            const float* __restrict__ w_comp,
                            const float* __restrict__ bases,
                            const float* __restrict__ loop_w,
                            const float* __restrict__ h_bias,
                            float* __restrict__ G) {
    __shared__ float sA[N_BASES * 3 * HD];   // A[b][k][o]
    const int tid = threadIdx.x;
    const int o = tid & 63;
    const int b = tid >> 6;                  // 0..3

    // A[b][k][o] = sum_i winrow_k[i] * bases[b,i,o]
    {
        float s0 = 0.f, s1 = 0.f, sb = 0.f;
        for (int i = 0; i < HD; i++) {
            float bv = bases[b * HD * HD + i * HD + o];
            s0 += W_in[i]      * bv;
            s1 += W_in[HD + i] * bv;
            sb += b_in[i]      * bv;
        }
        sA[(b * 3 + 0) * HD + o] = s0;
        sA[(b * 3 + 1) * HD + o] = s1;
        sA[(b * 3 + 2) * HD + o] = sb;
    }
    __syncthreads();

    // G[j][o] = sum_b w_comp[r,b] * A[b][k][o],  j = 3r+k
    for (int idx = tid; idx < 24 * HD; idx += 256) {
        int j = idx >> 6, oo = idx & 63;
        int r = j / 3, k = j % 3;
        float s = 0.f;
#pragma unroll
        for (int bb = 0; bb < N_BASES; bb++)
            s += w_comp[r * N_BASES + bb] * sA[(bb * 3 + k) * HD + oo];
        G[j * HD + oo] = s;
    }

    // self-loop columns j=24,25,26
    if (tid < 3 * HD) {
        int k = tid >> 6, oo = tid & 63;
        float s = 0.f;
        for (int i = 0; i < HD; i++) {
            float w = (k == 0) ? W_in[i] : (k == 1) ? W_in[HD + i] : b_in[i];
            s += w * loop_w[i * HD + oo];
        }
        if (k == 2) s += h_bias[oo];
        G[(24 + k) * HD + oo] = s;
    }
}

// ---------------------------------------------------------------------------
// D entry (v,r) = (fcW_v·g_{r,0}, fcW_v·g_{r,1}, fcW_v·g_{r,2}, 0) in fp16,
// v-major so each node's 8 relations share one 64B line.
// fc_W is a 12.8 MB one-shot stream -> nontemporal, keep L2 for D.
__global__ __launch_bounds__(256) void d_table_kernel(
        const vfloat4* __restrict__ fcW4,
        const float2* __restrict__ feat,
        const float* __restrict__ G,
        half8v* __restrict__ D16,        // index v*4 + j  (rel pair j)
        float* __restrict__ partD) {
    const int v = blockIdx.x * 256 + threadIdx.x;
    float part = 0.f;

    if (v < N_NODES) {
        vfloat4 Fr[16];
#pragma unroll
        for (int k = 0; k < 16; k++) Fr[k] = __builtin_nontemporal_load(&fcW4[v * 16 + k]);

        float s[27];
#pragma unroll
        for (int j = 0; j < 27; j++) {
            float acc = 0.f;
#pragma unroll
            for (int k = 0; k < 16; k++) {
                // uniform addresses -> scalar loads, broadcast
                float gx = G[j * HD + 4 * k + 0];
                float gy = G[j * HD + 4 * k + 1];
                float gz = G[j * HD + 4 * k + 2];
                float gw = G[j * HD + 4 * k + 3];
                acc += Fr[k].x * gx + Fr[k].y * gy + Fr[k].z * gz + Fr[k].w * gw;
            }
            s[j] = acc;
        }

        // pack rels (2j, 2j+1) into one 16B store; node v occupies D16[v*4 .. v*4+4)
#pragma unroll
        for (int j = 0; j < 4; j++) {
            half8v pk;
            pk[0] = (_Float16)s[6 * j + 0];
            pk[1] = (_Float16)s[6 * j + 1];
            pk[2] = (_Float16)s[6 * j + 2];
            pk[3] = (_Float16)0.f;
            pk[4] = (_Float16)s[6 * j + 3];
            pk[5] = (_Float16)s[6 * j + 4];
            pk[6] = (_Float16)s[6 * j + 5];
            pk[7] = (_Float16)0.f;
            D16[v * 4 + j] = pk;
        }

        float2 f = feat[v];
        part = s[24] * f.x + s[25] * f.y + s[26];
    }

    // shuffle block reduce (wave64), single barrier
    for (int off = 32; off; off >>= 1) part += __shfl_down(part, off);
    __shared__ float wred[4];
    if ((threadIdx.x & 63) == 0) wred[threadIdx.x >> 6] = part;
    __syncthreads();
    if (threadIdx.x == 0) partD[blockIdx.x] = wred[0] + wred[1] + wred[2] + wred[3];
}

// ---------------------------------------------------------------------------
// Pure gather over edges: 2 quads per thread, straight-line (branch-free
// clamped tail) -> 22 loads in flight per lane. fp16 D gathers (8B) from a
// 3.2 MB table. Writes one partial per block; no cross-block sync.
__global__ __launch_bounds__(256) void edge_gather_kernel(
        const vint4* __restrict__ src4,
        const vint4* __restrict__ dst4,
        const vint4* __restrict__ et4,
        const float2* __restrict__ feat,
        const half4v* __restrict__ D8,  // index v*8 + r
        float* __restrict__ partE) {
    const int t = blockIdx.x * 256 + threadIdx.x;    // t < 200192 <= NQUAD: always valid
    const int t2raw = t + NTHR_E;
    const int t2 = (t2raw < NQUAD) ? t2raw : (NQUAD - 1);
    const float w2 = (t2raw < NQUAD) ? 1.f : 0.f;

    vint4 uA = __builtin_nontemporal_load(&src4[t]);
    vint4 vA = __builtin_nontemporal_load(&dst4[t]);
    vint4 rA = __builtin_nontemporal_load(&et4[t]);
    vint4 uB = __builtin_nontemporal_load(&src4[t2]);
    vint4 vB = __builtin_nontemporal_load(&dst4[t2]);
    vint4 rB = __builtin_nontemporal_load(&et4[t2]);

    float2 fA0 = feat[uA.x];
    float2 fA1 = feat[uA.y];
    float2 fA2 = feat[uA.z];
    float2 fA3 = feat[uA.w];
    float2 fB0 = feat[uB.x];
    float2 fB1 = feat[uB.y];
    float2 fB2 = feat[uB.z];
    float2 fB3 = feat[uB.w];
    half4v hA0 = D8[vA.x * 8 + rA.x];
    half4v hA1 = D8[vA.y * 8 + rA.y];
    half4v hA2 = D8[vA.z * 8 + rA.z];
    half4v hA3 = D8[vA.w * 8 + rA.w];
    half4v hB0 = D8[vB.x * 8 + rB.x];
    half4v hB1 = D8[vB.y * 8 + rB.y];
    half4v hB2 = D8[vB.z * 8 + rB.z];
    half4v hB3 = D8[vB.w * 8 + rB.w];

    float sA = fA0.x * (float)hA0.x + fA0.y * (float)hA0.y + (float)hA0.z;
    sA      += fA1.x * (float)hA1.x + fA1.y * (float)hA1.y + (float)hA1.z;
    sA      += fA2.x * (float)hA2.x + fA2.y * (float)hA2.y + (float)hA2.z;
    sA      += fA3.x * (float)hA3.x + fA3.y * (float)hA3.y + (float)hA3.z;
    float sB = fB0.x * (float)hB0.x + fB0.y * (float)hB0.y + (float)hB0.z;
    sB      += fB1.x * (float)hB1.x + fB1.y * (float)hB1.y + (float)hB1.z;
    sB      += fB2.x * (float)hB2.x + fB2.y * (float)hB2.y + (float)hB2.z;
    sB      += fB3.x * (float)hB3.x + fB3.y * (float)hB3.y + (float)hB3.z;
    float s = sA + w2 * sB;

    // shuffle block reduce (wave64), single barrier
    for (int off = 32; off; off >>= 1) s += __shfl_down(s, off);
    __shared__ float wred[4];
    if ((threadIdx.x & 63) == 0) wred[threadIdx.x >> 6] = s;
    __syncthreads();
    if (threadIdx.x == 0) partE[blockIdx.x] = wred[0] + wred[1] + wred[2] + wred[3];
}

// ---------------------------------------------------------------------------
// Separate 1-block final reduce: inter-dispatch ordering guarantees
// visibility of all partials — no fences/atomics needed.
__global__ void final_kernel(const float* __restrict__ part,
                             const float* __restrict__ fc_b,
                             float* __restrict__ out) {
    float s = 0.f;
    for (int i = threadIdx.x; i < NB_D + NB_E; i += 256) s += part[i];
    for (int off = 32; off; off >>= 1) s += __shfl_down(s, off);
    __shared__ float wred[4];
    if ((threadIdx.x & 63) == 0) wred[threadIdx.x >> 6] = s;
    __syncthreads();
    if (threadIdx.x == 0) {
        float x = wred[0] + wred[1] + wred[2] + wred[3] + fc_b[0];
        out[0] = 1.0f / (1.0f + expf(-x));
    }
}

// ---------------------------------------------------------------------------
extern "C" void kernel_launch(void* const* d_in, const int* in_sizes, int n_in,
                              void* d_out, int out_size, void* d_ws, size_t ws_size,
                              hipStream_t stream) {
    const float* features = (const float*)d_in[0];
    const int*   src      = (const int*)d_in[1];
    const int*   dst      = (const int*)d_in[2];
    const int*   etype    = (const int*)d_in[3];
    const float* W_in     = (const float*)d_in[4];
    const float* b_in     = (const float*)d_in[5];
    const float* w_comp   = (const float*)d_in[6];
    const float* bases    = (const float*)d_in[7];
    const float* loop_w   = (const float*)d_in[8];
    const float* h_bias   = (const float*)d_in[9];
    const float* fc_W     = (const float*)d_in[10];
    const float* fc_b     = (const float*)d_in[11];

    float* ws   = (float*)d_ws;
    float* G    = ws + G_OFF;
    float* part = ws + PART_OFF;
    half8v* D16 = (half8v*)(ws + D_OFF);
    half4v* D8  = (half4v*)(ws + D_OFF);
    float* out  = (float*)d_out;

    prep_kernel<<<1, 256, 0, stream>>>(W_in, b_in, w_comp, bases, loop_w, h_bias, G);
    d_table_kernel<<<NB_D, 256, 0, stream>>>(
        (const vfloat4*)fc_W, (const float2*)features, G, D16, part);
    edge_gather_kernel<<<NB_E, 256, 0, stream>>>(
        (const vint4*)src, (const vint4*)dst, (const vint4*)etype,
        (const float2*)features, D8, part + NB_D);
    final_kernel<<<1, 256, 0, stream>>>(part, fc_b, out);
}